// Round 3
// baseline (165.119 us; speedup 1.0000x reference)
//
#include <hip/hip_runtime.h>

// Problem constants
#define DIM   1024
#define N_CLS 10
#define NROWS 16384
#define IMG   784

#define THREADS 512
#define WAVES   8
#define ROWS    64            // rows per block; lane == row
#define WIN4    32            // float4 per wave window (128 cols)
#define CH4     4             // float4 per chunk (16 cols)
#define NCHUNK  (WIN4 / CH4)  // 8

// ---------------------------------------------------------------------------
// Kernel 1: ref[c][d] = canon[c][d] / ||canon[c]|| for d<784, else 0.
// ---------------------------------------------------------------------------
__global__ void ref_prep_kernel(const float* __restrict__ canon,
                                float* __restrict__ ref) {
  __shared__ float red[256];
  const int c = blockIdx.x;
  const int t = threadIdx.x;
  const float* src = canon + c * IMG;

  float ss = 0.f;
  for (int d = t; d < IMG; d += 256) {
    float v = src[d];
    ss += v * v;
  }
  red[t] = ss;
  __syncthreads();
  for (int s = 128; s > 0; s >>= 1) {
    if (t < s) red[t] += red[t + s];
    __syncthreads();
  }
  const float inv = 1.0f / sqrtf(red[0]);

  for (int d = t; d < DIM; d += 256) {
    ref[c * DIM + d] = (d < IMG) ? src[d] * inv : 0.f;
  }
}

// ---------------------------------------------------------------------------
// Kernel 2: lane == row. 256 blocks x 512 threads (8 waves).
// Block owns 64 rows; wave w owns 128-col window [128w, 128w+128).
// z transposed through XOR-swizzled LDS (conflict-free b128); each lane
// accumulates its row's 20 dot-product partials in registers; ONE cross-wave
// combine at the end (vs per-row DPP reduction = the round-2 bottleneck).
// ref[c][d] is wave-uniform in the inner loop -> scalar/broadcast loads.
// ---------------------------------------------------------------------------
__global__ __launch_bounds__(THREADS, 2) void swaptest_kernel(
    const float* __restrict__ zre, const float* __restrict__ zim,
    const float* __restrict__ ref, float* __restrict__ out) {
  // Per-wave staging: 64 rows x 8 granules (4 re + 4 im), XOR-swizzled.
  // 8 waves x 512 float4 = 4096 float4 = 64 KB.
  __shared__ float4 lds4[WAVES * ROWS * 8];

  const int tid  = threadIdx.x;
  const int lane = tid & 63;
  const int wv   = __builtin_amdgcn_readfirstlane(tid >> 6);
  const int row0 = blockIdx.x * ROWS;

  const float4* zre4 = (const float4*)zre;
  const float4* zim4 = (const float4*)zim;
  const float4* ref4 = (const float4*)ref;

  float4* sw = lds4 + wv * (ROWS * 8);
  const int win4 = wv * WIN4;

  // staging mapping: iter j (0..3): row r = j*16 + (lane>>2), granule lane&3
  const int srow = lane >> 2;
  const int sgc  = lane & 3;
  const int sxor = srow & 7;  // == r & 7 (j*16 is 0 mod 8)

  float acc[2 * N_CLS];
#pragma unroll
  for (int v = 0; v < 2 * N_CLS; ++v) acc[v] = 0.f;

  // software pipeline: chunk k+1 global loads in flight during chunk k compute
  float4 cre[4], cim[4], nre[4], nim[4];
#pragma unroll
  for (int j = 0; j < 4; ++j) {
    const int g = (row0 + j * 16 + srow) * (DIM / 4) + win4 + sgc;
    cre[j] = zre4[g];
    cim[j] = zim4[g];
  }

#pragma unroll
  for (int k = 0; k < NCHUNK; ++k) {
    if (k + 1 < NCHUNK) {
#pragma unroll
      for (int j = 0; j < 4; ++j) {
        const int g =
            (row0 + j * 16 + srow) * (DIM / 4) + win4 + (k + 1) * CH4 + sgc;
        nre[j] = zre4[g];
        nim[j] = zim4[g];
      }
    }
    // stage chunk k (swizzled b128 writes; wave-private region, no barrier)
#pragma unroll
    for (int j = 0; j < 4; ++j) {
      const int r8 = (j * 16 + srow) * 8;
      sw[r8 + (sgc ^ sxor)]       = cre[j];
      sw[r8 + ((4 + sgc) ^ sxor)] = cim[j];
    }
    // compute chunk k: lane reads its row; ref is wave-uniform
#pragma unroll
    for (int g = 0; g < CH4; ++g) {
      const float4 zr = sw[lane * 8 + (g ^ (lane & 7))];
      const float4 zi = sw[lane * 8 + ((4 + g) ^ (lane & 7))];
#pragma unroll
      for (int c = 0; c < N_CLS; ++c) {
        const float4 rv = ref4[c * (DIM / 4) + win4 + k * CH4 + g];
        acc[2 * c] = fmaf(
            zr.w, rv.w,
            fmaf(zr.z, rv.z, fmaf(zr.y, rv.y, fmaf(zr.x, rv.x, acc[2 * c]))));
        acc[2 * c + 1] = fmaf(
            zi.w, rv.w,
            fmaf(zi.z, rv.z,
                 fmaf(zi.y, rv.y, fmaf(zi.x, rv.x, acc[2 * c + 1]))));
      }
    }
    if (k + 1 < NCHUNK) {
#pragma unroll
      for (int j = 0; j < 4; ++j) {
        cre[j] = nre[j];
        cim[j] = nim[j];
      }
    }
  }

  // ---- one-time cross-wave combine (aliases staging LDS; barriers guard) ---
  __syncthreads();
  float* ldsf = (float*)lds4;
  {
    float4* pw = (float4*)&ldsf[(wv * 64 + lane) * 20];
#pragma unroll
    for (int q = 0; q < 5; ++q)
      pw[q] = make_float4(acc[4 * q], acc[4 * q + 1], acc[4 * q + 2],
                          acc[4 * q + 3]);
  }
  __syncthreads();

  for (int idx = tid; idx < ROWS * N_CLS; idx += THREADS) {
    const int row = idx / N_CLS;
    const int c = idx - row * N_CLS;
    float are = 0.f, aim = 0.f;
#pragma unroll
    for (int w = 0; w < WAVES; ++w) {
      are += ldsf[(w * 64 + row) * 20 + 2 * c];
      aim += ldsf[(w * 64 + row) * 20 + 2 * c + 1];
    }
    out[(size_t)row0 * N_CLS + idx] = are * are + aim * aim;
  }
}

// ---------------------------------------------------------------------------
extern "C" void kernel_launch(void* const* d_in, const int* in_sizes, int n_in,
                              void* d_out, int out_size, void* d_ws,
                              size_t ws_size, hipStream_t stream) {
  const float* z_re = (const float*)d_in[0];
  const float* z_im = (const float*)d_in[1];
  const float* canon = (const float*)d_in[2];
  float* out = (float*)d_out;
  float* ref = (float*)d_ws;  // 10 * 1024 * 4 B = 40 KiB

  ref_prep_kernel<<<N_CLS, 256, 0, stream>>>(canon, ref);

  const int nblk = NROWS / ROWS;  // 256 blocks x 512 threads
  swaptest_kernel<<<nblk, THREADS, 0, stream>>>(z_re, z_im, ref, out);
}

// Round 4
// 159.133 us; speedup vs baseline: 1.0376x; 1.0376x over previous
//
#include <hip/hip_runtime.h>

// Problem constants
#define DIM    1024
#define DIM4   256        // float4 per row
#define N_CLS  10
#define NROWS  16384
#define IMG    784

#define THREADS  256
#define WAVES_PB 4        // waves per block; wave w owns cols [256w, 256w+256)
#define ROWS_PB  16       // rows per block; one 4-lane cluster per row
#define STEPS    16       // k-steps per wave; step = 16 cols (4 granules)
#define PSTRIDE  21       // padded LDS stride (floats) for partials (21 vs 20)

// ---------------------------------------------------------------------------
// Kernel 1: ref[c][d] = canon[c][d] / ||canon[c]|| for d<784, else 0.
// ---------------------------------------------------------------------------
__global__ void ref_prep_kernel(const float* __restrict__ canon,
                                float* __restrict__ ref) {
  __shared__ float red[256];
  const int c = blockIdx.x;
  const int t = threadIdx.x;
  const float* src = canon + c * IMG;

  float ss = 0.f;
  for (int d = t; d < IMG; d += 256) {
    float v = src[d];
    ss += v * v;
  }
  red[t] = ss;
  __syncthreads();
  for (int s = 128; s > 0; s >>= 1) {
    if (t < s) red[t] += red[t + s];
    __syncthreads();
  }
  const float inv = 1.0f / sqrtf(red[0]);

  for (int d = t; d < DIM; d += 256) {
    ref[c * DIM + d] = (d < IMG) ? src[d] * inv : 0.f;
  }
}

// ---------------------------------------------------------------------------
// Kernel 2: 1024 blocks x 256 threads (4 waves = 16 waves/CU at 4 blocks/CU).
// Wave w owns col window [256w, 256w+256). Within a wave, lanes form 16
// clusters of 4: cluster owns one row, lane q = L&3 covers granule 4s+q at
// step s -> every global load instruction = 16 rows x 64B contiguous
// segments (sequential streams, fully-consumed lines). Each lane keeps 20
// accumulators PERSISTENT over all K (no per-row reduction, no LDS
// transpose — the round-2/3 killers). ref (40 KB) is read per step from
// global: L2-hot, only 4 distinct addresses per instruction. ONE combine at
// block end through conflict-free padded LDS.
// ---------------------------------------------------------------------------
__global__ __launch_bounds__(THREADS, 4) void swaptest_kernel(
    const float* __restrict__ zre, const float* __restrict__ zim,
    const float* __restrict__ ref, float* __restrict__ out) {
  __shared__ float part[WAVES_PB * 64 * PSTRIDE];  // 21504 B

  const int tid  = threadIdx.x;
  const int lane = tid & 63;
  const int wv   = tid >> 6;
  const int q    = lane & 3;   // granule within cluster
  const int rloc = lane >> 2;  // row within block (0..15)

  const int row = blockIdx.x * ROWS_PB + rloc;

  const float4* zr4 = (const float4*)zre + (size_t)row * DIM4 + wv * 64 + q;
  const float4* zi4 = (const float4*)zim + (size_t)row * DIM4 + wv * 64 + q;
  const float4* rf4 = (const float4*)ref + wv * 64 + q;

  float accre[N_CLS], accim[N_CLS];
#pragma unroll
  for (int c = 0; c < N_CLS; ++c) {
    accre[c] = 0.f;
    accim[c] = 0.f;
  }

  // distance-1 software pipeline (statically resolved guards)
  float4 cre = zr4[0];
  float4 cim = zi4[0];
#pragma unroll
  for (int s = 0; s < STEPS; ++s) {
    float4 nre, nim;
    if (s + 1 < STEPS) {
      nre = zr4[(s + 1) * 4];
      nim = zi4[(s + 1) * 4];
    }
#pragma unroll
    for (int c = 0; c < N_CLS; ++c) {
      const float4 rv = rf4[c * DIM4 + s * 4];
      accre[c] = fmaf(
          cre.w, rv.w,
          fmaf(cre.z, rv.z, fmaf(cre.y, rv.y, fmaf(cre.x, rv.x, accre[c]))));
      accim[c] = fmaf(
          cim.w, rv.w,
          fmaf(cim.z, rv.z, fmaf(cim.y, rv.y, fmaf(cim.x, rv.x, accim[c]))));
    }
    if (s + 1 < STEPS) {
      cre = nre;
      cim = nim;
    }
  }

  // ---- one-time combine: 16 partials (4 waves x 4 cluster-lanes) per out ---
  {
    float* pp = &part[(wv * 64 + lane) * PSTRIDE];  // stride 21: conflict-free
#pragma unroll
    for (int c = 0; c < N_CLS; ++c) {
      pp[2 * c]     = accre[c];
      pp[2 * c + 1] = accim[c];
    }
  }
  __syncthreads();

  if (tid < ROWS_PB * N_CLS) {
    const int r = tid / N_CLS;
    const int c = tid - r * N_CLS;
    float are = 0.f, aim = 0.f;
#pragma unroll
    for (int w = 0; w < WAVES_PB; ++w) {
#pragma unroll
      for (int qq = 0; qq < 4; ++qq) {
        const float* sp = &part[(w * 64 + 4 * r + qq) * PSTRIDE];
        are += sp[2 * c];
        aim += sp[2 * c + 1];
      }
    }
    out[(size_t)(blockIdx.x * ROWS_PB + r) * N_CLS + c] = are * are + aim * aim;
  }
}

// ---------------------------------------------------------------------------
extern "C" void kernel_launch(void* const* d_in, const int* in_sizes, int n_in,
                              void* d_out, int out_size, void* d_ws,
                              size_t ws_size, hipStream_t stream) {
  const float* z_re = (const float*)d_in[0];
  const float* z_im = (const float*)d_in[1];
  const float* canon = (const float*)d_in[2];
  float* out = (float*)d_out;
  float* ref = (float*)d_ws;  // 10 * 1024 * 4 B = 40 KiB

  ref_prep_kernel<<<N_CLS, 256, 0, stream>>>(canon, ref);

  const int nblk = NROWS / ROWS_PB;  // 1024 blocks x 256 threads
  swaptest_kernel<<<nblk, THREADS, 0, stream>>>(z_re, z_im, ref, out);
}

// Round 5
// 152.376 us; speedup vs baseline: 1.0836x; 1.0443x over previous
//
#include <hip/hip_runtime.h>

// Problem constants
#define DIM    1024
#define N_CLS  10
#define NB     16         // B tile width (classes padded with zero columns)
#define NROWS  16384
#define IMG    784
#define K_HALF 512
#define CHUNKS 16         // K_HALF / 32

typedef __attribute__((ext_vector_type(8))) short sh8;  // 8 bf16 (A/B frag)
typedef __attribute__((ext_vector_type(4))) float f4;   // 4 f32  (C/D frag)

// RNE pack of two fp32 into one dword of two bf16 (lo in [15:0], hi in [31:16])
__device__ __forceinline__ unsigned f2bf2(float lo, float hi) {
  unsigned a = __float_as_uint(lo);
  unsigned b = __float_as_uint(hi);
  a += 0x7FFFu + ((a >> 16) & 1u);
  b += 0x7FFFu + ((b >> 16) & 1u);
  return (a >> 16) | (b & 0xFFFF0000u);
}

__device__ __forceinline__ unsigned short f2bf(float x) {
  unsigned a = __float_as_uint(x);
  a += 0x7FFFu + ((a >> 16) & 1u);
  return (unsigned short)(a >> 16);
}

__device__ __forceinline__ sh8 pack8(f4 v0, f4 v1) {
  union {
    unsigned u[4];
    sh8 s;
  } r;
  r.u[0] = f2bf2(v0.x, v0.y);
  r.u[1] = f2bf2(v0.z, v0.w);
  r.u[2] = f2bf2(v1.x, v1.y);
  r.u[3] = f2bf2(v1.z, v1.w);
  return r.s;
}

// ---------------------------------------------------------------------------
// Kernel 1: refb[c][d] = bf16( canon[c][d] / ||canon[c]|| ), zero-padded to
// d<DIM and c<NB. One block per (padded) class; entire buffer rewritten every
// launch (d_ws is re-poisoned by the harness).
// ---------------------------------------------------------------------------
__global__ void ref_prep_kernel(const float* __restrict__ canon,
                                unsigned short* __restrict__ refb) {
  __shared__ float red[256];
  const int c = blockIdx.x;   // 0..NB-1 (block-uniform)
  const int t = threadIdx.x;

  float inv = 0.f;
  if (c < N_CLS) {
    const float* src = canon + c * IMG;
    float ss = 0.f;
    for (int d = t; d < IMG; d += 256) {
      float v = src[d];
      ss += v * v;
    }
    red[t] = ss;
    __syncthreads();
    for (int s = 128; s > 0; s >>= 1) {
      if (t < s) red[t] += red[t + s];
      __syncthreads();
    }
    inv = 1.0f / sqrtf(red[0]);
  }

  for (int d = t; d < DIM; d += 256) {
    float v = (c < N_CLS && d < IMG) ? canon[c * IMG + d] * inv : 0.f;
    refb[c * DIM + d] = f2bf(v);
  }
}

// ---------------------------------------------------------------------------
// Kernel 2: MFMA GEMM  C[16384,16] = z * refb^T, fused re/im + square-sum.
// 512 blocks x 256 threads (4 waves). Wave (st,kh): stripe st (16 rows) of
// this block, K-half kh. B operand (refb, [n][k] row-major = B^T) preloaded
// into 64 VGPRs ONCE -> the K-loop's only memory ops are streaming z loads
// (4 coalesced float4 per chunk-32: 16 rows x 64B segments), depth-2
// pipelined. No per-step dependent cache loads (the R1-R4 serializer), no
// per-row reduction (the R2 VALU killer). One 4KB LDS combine at block end.
// Fragment layouts (m89/m91-verified): A[m=L&15][k=(L>>4)*8+j],
// B[k=(L>>4)*8+j][n=L&15], C col=lane&15 row=(lane>>4)*4+reg.
// __launch_bounds__(256,2): 256-VGPR cap so the allocator KEEPS the pipeline
// (R3/R4's (256,4)=128-cap made it sink all prefetches; VGPR_Count 52-64).
// ---------------------------------------------------------------------------
__global__ __launch_bounds__(256, 2) void swaptest_kernel(
    const float* __restrict__ zre, const float* __restrict__ zim,
    const unsigned short* __restrict__ refb, float* __restrict__ out) {
  __shared__ float part[8][2][64];  // [reg(4re+4im)][stripe][lane] 4 KB

  const int tid  = threadIdx.x;
  const int lane = tid & 63;
  const int wv   = tid >> 6;
  const int st   = wv >> 1;    // stripe within block (0/1)
  const int kh   = wv & 1;     // K-half (0/1)
  const int mrow = lane & 15;  // A row within stripe == B class col
  const int kq   = lane >> 4;  // k-quad (0..3)

  const int row   = blockIdx.x * 32 + st * 16 + mrow;
  const int kbase = kh * K_HALF + kq * 8;

  // --- preload all B fragments: 16 chunks x 4 VGPRs = 64 VGPRs ---
  sh8 bfrag[CHUNKS];
#pragma unroll
  for (int i = 0; i < CHUNKS; ++i)
    bfrag[i] = *(const sh8*)&refb[mrow * DIM + kbase + i * 32];

  const float* pre = zre + (size_t)row * DIM + kbase;
  const float* pim = zim + (size_t)row * DIM + kbase;

  f4 accre = {0.f, 0.f, 0.f, 0.f};
  f4 accim = {0.f, 0.f, 0.f, 0.f};

  // depth-2 software pipeline over 16 chunks of K=32
  f4 cre0 = *(const f4*)(pre);
  f4 cre1 = *(const f4*)(pre + 4);
  f4 cim0 = *(const f4*)(pim);
  f4 cim1 = *(const f4*)(pim + 4);
#pragma unroll
  for (int i = 0; i < CHUNKS; ++i) {
    f4 nre0, nre1, nim0, nim1;
    if (i + 1 < CHUNKS) {
      nre0 = *(const f4*)(pre + (i + 1) * 32);
      nre1 = *(const f4*)(pre + (i + 1) * 32 + 4);
      nim0 = *(const f4*)(pim + (i + 1) * 32);
      nim1 = *(const f4*)(pim + (i + 1) * 32 + 4);
    }
    const sh8 a_re = pack8(cre0, cre1);
    const sh8 a_im = pack8(cim0, cim1);
    accre = __builtin_amdgcn_mfma_f32_16x16x32_bf16(a_re, bfrag[i], accre,
                                                    0, 0, 0);
    accim = __builtin_amdgcn_mfma_f32_16x16x32_bf16(a_im, bfrag[i], accim,
                                                    0, 0, 0);
    if (i + 1 < CHUNKS) {
      cre0 = nre0; cre1 = nre1;
      cim0 = nim0; cim1 = nim1;
    }
  }

  // --- combine K-halves (lane->C-element map identical across waves) ---
  if (kh == 1) {
#pragma unroll
    for (int r = 0; r < 4; ++r) {
      part[r][st][lane]     = accre[r];
      part[4 + r][st][lane] = accim[r];
    }
  }
  __syncthreads();

  if (kh == 0 && mrow < N_CLS) {
    const int orow0 = blockIdx.x * 32 + st * 16 + kq * 4;
#pragma unroll
    for (int r = 0; r < 4; ++r) {
      const float re = accre[r] + part[r][st][lane];
      const float im = accim[r] + part[4 + r][st][lane];
      out[(size_t)(orow0 + r) * N_CLS + mrow] = re * re + im * im;
    }
  }
}

// ---------------------------------------------------------------------------
extern "C" void kernel_launch(void* const* d_in, const int* in_sizes, int n_in,
                              void* d_out, int out_size, void* d_ws,
                              size_t ws_size, hipStream_t stream) {
  const float* z_re = (const float*)d_in[0];
  const float* z_im = (const float*)d_in[1];
  const float* canon = (const float*)d_in[2];
  float* out = (float*)d_out;
  unsigned short* refb = (unsigned short*)d_ws;  // 16 * 1024 * 2 B = 32 KiB

  ref_prep_kernel<<<NB, 256, 0, stream>>>(canon, refb);

  const int nblk = NROWS / 32;  // 512 blocks x 256 threads
  swaptest_kernel<<<nblk, 256, 0, stream>>>(z_re, z_im, refb, out);
}